// Round 1
// baseline (1196.335 us; speedup 1.0000x reference)
//
#include <hip/hip_runtime.h>

// Problem constants (B, Ns, Nt, Fs, Ft, Fo fixed by the reference)
#define BB 4
#define NS 4096
#define NT 4096
#define FS 256
#define FT 256
#define FO 64
#define ALPHA 0.2f
#define OUT_SLOPE 0.01f
#define TI 32   // target rows per block in k_main

__device__ __forceinline__ float leaky(float x, float s) { return x > 0.f ? x : s * x; }

// wa[f] = sum_o Wt[f, o] * a[FO + o]   (256-vector)
__global__ void k_wa(const float* __restrict__ Wt, const float* __restrict__ a,
                     float* __restrict__ wa) {
  int f = threadIdx.x;  // 0..255
  float acc = 0.f;
#pragma unroll
  for (int o = 0; o < FO; ++o) acc += Wt[f * FO + o] * a[FO + o];
  wa[f] = acc;
}

// t[row] = dot(h[row, :256], wa)   one wave per row
__global__ __launch_bounds__(256) void k_t(const float* __restrict__ h,
                                           const float* __restrict__ wa,
                                           float* __restrict__ tvec) {
  int lane = threadIdx.x & 63, wave = threadIdx.x >> 6;
  int row = blockIdx.x * 4 + wave;  // 0..B*NT-1
  const float4* hp = (const float4*)(h + (size_t)row * FT);
  const float4* wp = (const float4*)wa;
  float4 hv = hp[lane], wv = wp[lane];
  float acc = hv.x * wv.x + hv.y * wv.y + hv.z * wv.z + hv.w * wv.w;
#pragma unroll
  for (int off = 32; off; off >>= 1) acc += __shfl_down(acc, off);
  if (lane == 0) tvec[row] = acc;
}

// per-batch max of t (used as the softmax shift; exact max not required, any
// per-row-valid upper bound works since softmax shift cancels)
__global__ __launch_bounds__(256) void k_tmax(const float* __restrict__ tvec,
                                              float* __restrict__ tmax) {
  __shared__ float red[256];
  int b = blockIdx.x, tid = threadIdx.x;
  float m = -3.0e38f;
  for (int j = tid; j < NS; j += 256) m = fmaxf(m, tvec[b * NS + j]);
  red[tid] = m;
  __syncthreads();
  for (int s = 128; s; s >>= 1) {
    if (tid < s) red[tid] = fmaxf(red[tid], red[tid + s]);
    __syncthreads();
  }
  if (tid == 0) tmax[b] = red[0];
}

// Ws_ctx[row, f] = dot(ctx[row, :256], Ws[:, f]); also s[row] = Ws_ctx[row,:]@a[:64]
// one wave per 4 rows (amortizes Ws loads), 64 lanes = f
__global__ __launch_bounds__(256) void k_wsctx(const float* __restrict__ ctx,
                                               const float* __restrict__ Ws,
                                               const float* __restrict__ a,
                                               float* __restrict__ wsctx,
                                               float* __restrict__ svec) {
  const int f = threadIdx.x & 63, wave = threadIdx.x >> 6;
  const int row0 = blockIdx.x * 16 + wave * 4;
  const float4* c0 = (const float4*)(ctx + (size_t)(row0 + 0) * FS);
  const float4* c1 = (const float4*)(ctx + (size_t)(row0 + 1) * FS);
  const float4* c2 = (const float4*)(ctx + (size_t)(row0 + 2) * FS);
  const float4* c3 = (const float4*)(ctx + (size_t)(row0 + 3) * FS);
  float r0 = 0.f, r1 = 0.f, r2 = 0.f, r3 = 0.f;
#pragma unroll 2
  for (int k4 = 0; k4 < FS / 4; ++k4) {
    const float w0 = Ws[(k4 * 4 + 0) * FO + f];
    const float w1 = Ws[(k4 * 4 + 1) * FO + f];
    const float w2 = Ws[(k4 * 4 + 2) * FO + f];
    const float w3 = Ws[(k4 * 4 + 3) * FO + f];
    float4 x;
    x = c0[k4]; r0 += x.x * w0 + x.y * w1 + x.z * w2 + x.w * w3;
    x = c1[k4]; r1 += x.x * w0 + x.y * w1 + x.z * w2 + x.w * w3;
    x = c2[k4]; r2 += x.x * w0 + x.y * w1 + x.z * w2 + x.w * w3;
    x = c3[k4]; r3 += x.x * w0 + x.y * w1 + x.z * w2 + x.w * w3;
  }
  wsctx[(size_t)(row0 + 0) * FO + f] = r0;
  wsctx[(size_t)(row0 + 1) * FO + f] = r1;
  wsctx[(size_t)(row0 + 2) * FO + f] = r2;
  wsctx[(size_t)(row0 + 3) * FO + f] = r3;
  const float af = a[f];
  float s0 = r0 * af, s1 = r1 * af, s2 = r2 * af, s3 = r3 * af;
#pragma unroll
  for (int off = 32; off; off >>= 1) {
    s0 += __shfl_down(s0, off);
    s1 += __shfl_down(s1, off);
    s2 += __shfl_down(s2, off);
    s3 += __shfl_down(s3, off);
  }
  if (f == 0) {
    svec[row0 + 0] = s0;
    svec[row0 + 1] = s1;
    svec[row0 + 2] = s2;
    svec[row0 + 3] = s3;
  }
}

// Main: per 32-row tile, single pass over j (fixed shift c_i = leaky(s_i+tmax_b)):
//   w[i][j] = adj ? exp(leaky(s_i + t_j) - c_i) : 0
//   l[i]    = sum_j w ; out[i,f] = leaky( (sum_j w * Ws_ctx[j,f]) / l[i], 0.01 )
__global__ __launch_bounds__(128) void k_main(const int* __restrict__ adj,
                                              const float* __restrict__ wsctx,
                                              const float* __restrict__ svec,
                                              const float* __restrict__ tvec,
                                              const float* __restrict__ tmax,
                                              float* __restrict__ out) {
  __shared__ __align__(16) float wS[64 * 36];  // [j][row] stride 36 (b128-aligned)
  __shared__ float s_sh[TI], c_sh[TI], l_sh[TI];

  const int tid = threadIdx.x;
  const int lane = tid & 63;
  const int wave = tid >> 6;  // 0..1
  const int fg = tid & 15;    // f-group: cols fg*4..fg*4+3
  const int rg = tid >> 4;    // row-group 0..7: rows rg*4..rg*4+3

  const int b = blockIdx.x >> 7;          // 128 blocks per batch
  const int i0 = (blockIdx.x & 127) * TI;

  if (tid < TI) {
    float s = svec[b * NS + i0 + tid];
    s_sh[tid] = s;
    c_sh[tid] = leaky(s + tmax[b], ALPHA);
  }
  __syncthreads();

  float acc[16];
  float lacc[16];
#pragma unroll
  for (int k = 0; k < 16; ++k) { acc[k] = 0.f; lacc[k] = 0.f; }

  // w-phase: wave owns 16 contiguous rows so 4 w's pack into one b128 write
  const size_t adj_row0 = ((size_t)(b * NT + i0 + wave * 16)) * NS;

  for (int jc = 0; jc < NS / 64; ++jc) {
    const int j = jc * 64 + lane;
    const float tj = tvec[b * NS + j];
    {
      const int* ap = adj + adj_row0 + j;
#pragma unroll
      for (int rr = 0; rr < 4; ++rr) {
        float4 wv;
        float* wp = (float*)&wv;
#pragma unroll
        for (int q = 0; q < 4; ++q) {
          const int r = wave * 16 + rr * 4 + q;
          const int av = ap[(size_t)(rr * 4 + q) * NS];   // coalesced over lanes (j)
          const float e = leaky(s_sh[r] + tj, ALPHA);
          const float w = (av > 0) ? __expf(e - c_sh[r]) : 0.f;
          lacc[rr * 4 + q] += w;
          wp[q] = w;
        }
        *(float4*)&wS[lane * 36 + wave * 16 + rr * 4] = wv;
      }
    }
    __syncthreads();
    {
      const float* vbase = wsctx + ((size_t)(b * NS + jc * 64)) * FO + fg * 4;
#pragma unroll 4
      for (int jl = 0; jl < 64; ++jl) {
        const float4 w4 = *(const float4*)&wS[jl * 36 + rg * 4];            // 4 rows
        const float4 v4 = *(const float4*)(vbase + (size_t)jl * FO);        // 4 cols
        acc[0]  += w4.x * v4.x;  acc[1]  += w4.x * v4.y;  acc[2]  += w4.x * v4.z;  acc[3]  += w4.x * v4.w;
        acc[4]  += w4.y * v4.x;  acc[5]  += w4.y * v4.y;  acc[6]  += w4.y * v4.z;  acc[7]  += w4.y * v4.w;
        acc[8]  += w4.z * v4.x;  acc[9]  += w4.z * v4.y;  acc[10] += w4.z * v4.z;  acc[11] += w4.z * v4.w;
        acc[12] += w4.w * v4.x;  acc[13] += w4.w * v4.y;  acc[14] += w4.w * v4.z;  acc[15] += w4.w * v4.w;
      }
    }
    __syncthreads();
  }

  // reduce l over lanes (j) for the wave's 16 rows
#pragma unroll
  for (int k = 0; k < 16; ++k) {
    float v = lacc[k];
#pragma unroll
    for (int off = 32; off; off >>= 1) v += __shfl_down(v, off);
    if (lane == 0) l_sh[wave * 16 + k] = v;
  }
  __syncthreads();

#pragma unroll
  for (int q = 0; q < 4; ++q) {
    const int r = rg * 4 + q;
    const float inv = 1.f / l_sh[r];
    float4 o;
    o.x = leaky(acc[q * 4 + 0] * inv, OUT_SLOPE);
    o.y = leaky(acc[q * 4 + 1] * inv, OUT_SLOPE);
    o.z = leaky(acc[q * 4 + 2] * inv, OUT_SLOPE);
    o.w = leaky(acc[q * 4 + 3] * inv, OUT_SLOPE);
    *(float4*)(out + ((size_t)(b * NT + i0 + r)) * FO + fg * 4) = o;
  }
}

extern "C" void kernel_launch(void* const* d_in, const int* in_sizes, int n_in,
                              void* d_out, int out_size, void* d_ws, size_t ws_size,
                              hipStream_t stream) {
  const float* h   = (const float*)d_in[0];  // [B, Nt, Ft]
  const float* ctx = (const float*)d_in[1];  // [B, Ns, Fs]
  const int*   adj = (const int*)d_in[2];    // [B, Nt, Ns]
  const float* Ws  = (const float*)d_in[3];  // [Fs, Fo]
  const float* Wt  = (const float*)d_in[4];  // [Ft, Fo]
  const float* a   = (const float*)d_in[5];  // [2*Fo, 1]
  float* out = (float*)d_out;                // [B, Nt, Fo] fp32
  float* ws = (float*)d_ws;

  // workspace layout (floats): needs ~4.33 MB
  float* wsctx = ws;                         // B*NS*FO = 1048576
  float* tvec  = ws + 1048576;               // 16384
  float* svec  = ws + 1048576 + 16384;       // 16384
  float* wa    = ws + 1048576 + 32768;       // 256
  float* tmax  = wa + 256;                   // 4

  k_wa<<<1, 256, 0, stream>>>(Wt, a, wa);
  k_t<<<(BB * NT) / 4, 256, 0, stream>>>(h, wa, tvec);
  k_tmax<<<BB, 256, 0, stream>>>(tvec, tmax);
  k_wsctx<<<(BB * NS) / 16, 256, 0, stream>>>(ctx, Ws, a, wsctx, svec);
  k_main<<<(BB * NT) / TI, 128, 0, stream>>>(adj, wsctx, svec, tvec, tmax, out);
}

// Round 2
// 567.938 us; speedup vs baseline: 2.1065x; 2.1065x over previous
//
#include <hip/hip_runtime.h>

// Problem constants (fixed by the reference)
#define BB 4
#define NS 4096
#define NT 4096
#define FS 256
#define FT 256
#define FO 64
#define ALPHA 0.2f
#define OUT_SLOPE 0.01f
#define JSPLIT 4   // j-range split across blocks (partials combined via atomics)
#define TI 64      // target rows per block in k_part

__device__ __forceinline__ float leaky(float x, float s) { return x > 0.f ? x : s * x; }

// wa[f] = sum_o Wt[f, o] * a[FO + o]   (256-vector)
__global__ void k_wa(const float* __restrict__ Wt, const float* __restrict__ a,
                     float* __restrict__ wa) {
  int f = threadIdx.x;  // 0..255
  float acc = 0.f;
#pragma unroll
  for (int o = 0; o < FO; ++o) acc += Wt[f * FO + o] * a[FO + o];
  wa[f] = acc;
}

// t[row] = dot(h[row, :256], wa)   one wave per row
__global__ __launch_bounds__(256) void k_t(const float* __restrict__ h,
                                           const float* __restrict__ wa,
                                           float* __restrict__ tvec) {
  int lane = threadIdx.x & 63, wave = threadIdx.x >> 6;
  int row = blockIdx.x * 4 + wave;  // 0..B*NT-1
  const float4* hp = (const float4*)(h + (size_t)row * FT);
  const float4* wp = (const float4*)wa;
  float4 hv = hp[lane], wv = wp[lane];
  float acc = hv.x * wv.x + hv.y * wv.y + hv.z * wv.z + hv.w * wv.w;
#pragma unroll
  for (int off = 32; off; off >>= 1) acc += __shfl_down(acc, off);
  if (lane == 0) tvec[row] = acc;
}

// per-batch max of t (softmax shift; any per-row-valid upper bound works)
__global__ __launch_bounds__(256) void k_tmax(const float* __restrict__ tvec,
                                              float* __restrict__ tmax) {
  __shared__ float red[256];
  int b = blockIdx.x, tid = threadIdx.x;
  float m = -3.0e38f;
  for (int j = tid; j < NS; j += 256) m = fmaxf(m, tvec[b * NS + j]);
  red[tid] = m;
  __syncthreads();
  for (int s = 128; s; s >>= 1) {
    if (tid < s) red[tid] = fmaxf(red[tid], red[tid + s]);
    __syncthreads();
  }
  if (tid == 0) tmax[b] = red[0];
}

// Ws_ctx[row, f] = dot(ctx[row, :256], Ws[:, f]); also s[row] = Ws_ctx[row,:]@a[:64]
__global__ __launch_bounds__(256) void k_wsctx(const float* __restrict__ ctx,
                                               const float* __restrict__ Ws,
                                               const float* __restrict__ a,
                                               float* __restrict__ wsctx,
                                               float* __restrict__ svec) {
  const int f = threadIdx.x & 63, wave = threadIdx.x >> 6;
  const int row0 = blockIdx.x * 16 + wave * 4;
  const float4* c0 = (const float4*)(ctx + (size_t)(row0 + 0) * FS);
  const float4* c1 = (const float4*)(ctx + (size_t)(row0 + 1) * FS);
  const float4* c2 = (const float4*)(ctx + (size_t)(row0 + 2) * FS);
  const float4* c3 = (const float4*)(ctx + (size_t)(row0 + 3) * FS);
  float r0 = 0.f, r1 = 0.f, r2 = 0.f, r3 = 0.f;
#pragma unroll 2
  for (int k4 = 0; k4 < FS / 4; ++k4) {
    const float w0 = Ws[(k4 * 4 + 0) * FO + f];
    const float w1 = Ws[(k4 * 4 + 1) * FO + f];
    const float w2 = Ws[(k4 * 4 + 2) * FO + f];
    const float w3 = Ws[(k4 * 4 + 3) * FO + f];
    float4 x;
    x = c0[k4]; r0 += x.x * w0 + x.y * w1 + x.z * w2 + x.w * w3;
    x = c1[k4]; r1 += x.x * w0 + x.y * w1 + x.z * w2 + x.w * w3;
    x = c2[k4]; r2 += x.x * w0 + x.y * w1 + x.z * w2 + x.w * w3;
    x = c3[k4]; r3 += x.x * w0 + x.y * w1 + x.z * w2 + x.w * w3;
  }
  wsctx[(size_t)(row0 + 0) * FO + f] = r0;
  wsctx[(size_t)(row0 + 1) * FO + f] = r1;
  wsctx[(size_t)(row0 + 2) * FO + f] = r2;
  wsctx[(size_t)(row0 + 3) * FO + f] = r3;
  const float af = a[f];
  float s0 = r0 * af, s1 = r1 * af, s2 = r2 * af, s3 = r3 * af;
#pragma unroll
  for (int off = 32; off; off >>= 1) {
    s0 += __shfl_down(s0, off);
    s1 += __shfl_down(s1, off);
    s2 += __shfl_down(s2, off);
    s3 += __shfl_down(s3, off);
  }
  if (f == 0) {
    svec[row0 + 0] = s0;
    svec[row0 + 1] = s1;
    svec[row0 + 2] = s2;
    svec[row0 + 3] = s3;
  }
}

// Partial-softmax weighted sum over a 1/JSPLIT j-range.
// Fixed per-row shift c_i = leaky(s_i + tmax_b) makes numerator+denominator
// linear in j => partials combine with atomicAdd.
// Block: 256 thr (4 waves), TI=64 target rows, j chunk of 64 per iteration.
__global__ __launch_bounds__(256) void k_part(const int* __restrict__ adj,
                                              const float* __restrict__ wsctx,
                                              const float* __restrict__ svec,
                                              const float* __restrict__ tvec,
                                              const float* __restrict__ tmax,
                                              float* __restrict__ outacc,
                                              float* __restrict__ lvec) {
  __shared__ __align__(16) float wS[64 * 68];  // [j][row], stride 68 (16B-aligned)
  __shared__ float s_sh[TI], c_sh[TI];

  const int tid = threadIdx.x;
  const int lane = tid & 63;
  const int wave = tid >> 6;      // 0..3, owns rows wave*16..wave*16+15
  const int tile = blockIdx.x >> 2;   // 256 row-tiles
  const int js = blockIdx.x & 3;      // j-split id
  const int b = tile >> 6;            // 64 tiles per batch
  const int i0 = (tile & 63) * TI;

  if (tid < TI) {
    float s = svec[b * NS + i0 + tid];
    s_sh[tid] = s;
    c_sh[tid] = leaky(s + tmax[b], ALPHA);
  }
  __syncthreads();

  // w-phase thread mapping: j4 = lane&15 (16 groups x 4 consecutive j),
  //                         rr = lane>>4 (4 row-subgroups x 4 rows)
  const int j4 = lane & 15, rr = lane >> 4;
  // matmul-phase mapping: fg = tid&15 (cols fg*4..+3), rg = tid>>4 (rows rg*4..+3)
  const int fg = tid & 15, rg = tid >> 4;

  float acc[16];
  float lacc[4];
#pragma unroll
  for (int k = 0; k < 16; ++k) acc[k] = 0.f;
#pragma unroll
  for (int k = 0; k < 4; ++k) lacc[k] = 0.f;

  const int row0 = wave * 16 + rr * 4;

  for (int jc = 0; jc < (NS / JSPLIT) / 64; ++jc) {
    const int jbase = js * (NS / JSPLIT) + jc * 64;
    // ---- w-phase: compute 4j x 4r masked-exp weights per lane ----
    const float4 t4 = *(const float4*)(tvec + b * NS + jbase + j4 * 4);
    const size_t arow = (size_t)(b * NT + i0 + row0) * NS + jbase + j4 * 4;
    float wv[4][4];  // [r][q]
#pragma unroll
    for (int r = 0; r < 4; ++r) {
      const int4 a4 = *(const int4*)(adj + arow + (size_t)r * NS);
      const float sr = s_sh[row0 + r];
      const float cr = c_sh[row0 + r];
      const float w0 = (a4.x > 0) ? __expf(leaky(sr + t4.x, ALPHA) - cr) : 0.f;
      const float w1 = (a4.y > 0) ? __expf(leaky(sr + t4.y, ALPHA) - cr) : 0.f;
      const float w2 = (a4.z > 0) ? __expf(leaky(sr + t4.z, ALPHA) - cr) : 0.f;
      const float w3 = (a4.w > 0) ? __expf(leaky(sr + t4.w, ALPHA) - cr) : 0.f;
      wv[r][0] = w0; wv[r][1] = w1; wv[r][2] = w2; wv[r][3] = w3;
      lacc[r] += w0 + w1 + w2 + w3;
    }
#pragma unroll
    for (int q = 0; q < 4; ++q) {
      float4 o = make_float4(wv[0][q], wv[1][q], wv[2][q], wv[3][q]);
      *(float4*)&wS[(j4 * 4 + q) * 68 + row0] = o;
    }
    __syncthreads();
    // ---- matmul phase: 4r x 4f register tile over the 64-j chunk ----
    {
      const float* vbase = wsctx + ((size_t)(b * NS + jbase)) * FO + fg * 4;
#pragma unroll 4
      for (int jl = 0; jl < 64; ++jl) {
        const float4 w4 = *(const float4*)&wS[jl * 68 + rg * 4];
        const float4 v4 = *(const float4*)(vbase + (size_t)jl * FO);
        acc[0]  += w4.x * v4.x;  acc[1]  += w4.x * v4.y;  acc[2]  += w4.x * v4.z;  acc[3]  += w4.x * v4.w;
        acc[4]  += w4.y * v4.x;  acc[5]  += w4.y * v4.y;  acc[6]  += w4.y * v4.z;  acc[7]  += w4.y * v4.w;
        acc[8]  += w4.z * v4.x;  acc[9]  += w4.z * v4.y;  acc[10] += w4.z * v4.z;  acc[11] += w4.z * v4.w;
        acc[12] += w4.w * v4.x;  acc[13] += w4.w * v4.y;  acc[14] += w4.w * v4.z;  acc[15] += w4.w * v4.w;
      }
    }
    __syncthreads();
  }

  // ---- partial denominator: reduce lacc over the 16 j4-lanes per row ----
#pragma unroll
  for (int r = 0; r < 4; ++r) {
    float v = lacc[r];
    v += __shfl_down(v, 8);
    v += __shfl_down(v, 4);
    v += __shfl_down(v, 2);
    v += __shfl_down(v, 1);
    if (j4 == 0) atomicAdd(lvec + b * NT + i0 + row0 + r, v);
  }

  // ---- partial numerator: atomic-accumulate the 4r x 4f register tile ----
#pragma unroll
  for (int k = 0; k < 16; ++k) {
    const int row = rg * 4 + (k >> 2);
    const int f = fg * 4 + (k & 3);
    atomicAdd(outacc + ((size_t)(b * NT + i0 + row)) * FO + f, acc[k]);
  }
}

// out[i,f] = leaky(out[i,f] / l[i], 0.01), vectorized float4
__global__ __launch_bounds__(256) void k_fin(float* __restrict__ out,
                                             const float* __restrict__ lvec) {
  const int idx = blockIdx.x * 256 + threadIdx.x;   // float4 index
  const float inv = 1.f / lvec[idx >> 4];           // 16 float4 per row
  float4 v = ((float4*)out)[idx];
  v.x = leaky(v.x * inv, OUT_SLOPE);
  v.y = leaky(v.y * inv, OUT_SLOPE);
  v.z = leaky(v.z * inv, OUT_SLOPE);
  v.w = leaky(v.w * inv, OUT_SLOPE);
  ((float4*)out)[idx] = v;
}

extern "C" void kernel_launch(void* const* d_in, const int* in_sizes, int n_in,
                              void* d_out, int out_size, void* d_ws, size_t ws_size,
                              hipStream_t stream) {
  const float* h   = (const float*)d_in[0];  // [B, Nt, Ft]
  const float* ctx = (const float*)d_in[1];  // [B, Ns, Fs]
  const int*   adj = (const int*)d_in[2];    // [B, Nt, Ns]
  const float* Ws  = (const float*)d_in[3];  // [Fs, Fo]
  const float* Wt  = (const float*)d_in[4];  // [Ft, Fo]
  const float* a   = (const float*)d_in[5];  // [2*Fo, 1]
  float* out = (float*)d_out;                // [B, Nt, Fo] fp32
  float* ws = (float*)d_ws;

  // workspace layout (floats): ~4.46 MB
  float* wsctx = ws;                          // B*NS*FO = 1048576
  float* tvec  = wsctx + 1048576;             // 16384
  float* svec  = tvec + 16384;                // 16384
  float* lvec  = svec + 16384;                // 16384 (softmax denominators)
  float* wa    = lvec + 16384;                // 256
  float* tmax  = wa + 256;                    // 4

  hipMemsetAsync(out, 0, (size_t)BB * NT * FO * sizeof(float), stream);
  hipMemsetAsync(lvec, 0, (size_t)BB * NT * sizeof(float), stream);

  k_wa<<<1, 256, 0, stream>>>(Wt, a, wa);
  k_t<<<(BB * NT) / 4, 256, 0, stream>>>(h, wa, tvec);
  k_tmax<<<BB, 256, 0, stream>>>(tvec, tmax);
  k_wsctx<<<(BB * NS) / 16, 256, 0, stream>>>(ctx, Ws, a, wsctx, svec);
  k_part<<<(BB * NT / TI) * JSPLIT, 256, 0, stream>>>(adj, wsctx, svec, tvec, tmax, out, lvec);
  k_fin<<<(BB * NT * FO / 4) / 256, 256, 0, stream>>>(out, lvec);
}

// Round 3
// 486.015 us; speedup vs baseline: 2.4615x; 1.1686x over previous
//
#include <hip/hip_runtime.h>

// Problem constants (fixed by the reference)
#define BB 4
#define NS 4096
#define NT 4096
#define FS 256
#define FT 256
#define FO 64
#define ALPHA 0.2f
#define OUT_SLOPE 0.01f
#define JSPLIT 4   // j-range split across blocks (partials combined in k_fin)

typedef __attribute__((ext_vector_type(8))) short short8;
typedef __attribute__((ext_vector_type(4))) float floatx4;

__device__ __forceinline__ float leaky(float x, float s) { return x > 0.f ? x : s * x; }
// leaky with slope<1 == max(x, slope*x)
__device__ __forceinline__ float leaky_max(float x, float s) { return fmaxf(x, s * x); }

// fp32 -> bf16 with round-to-nearest-even
__device__ __forceinline__ short f2bf(float x) {
  union { float f; unsigned u; } c; c.f = x;
  unsigned r = c.u + 0x7fffu + ((c.u >> 16) & 1u);
  return (short)(r >> 16);
}

// wa[f] = sum_o Wt[f, o] * a[FO + o]   (256-vector)
__global__ void k_wa(const float* __restrict__ Wt, const float* __restrict__ a,
                     float* __restrict__ wa) {
  int f = threadIdx.x;  // 0..255
  float acc = 0.f;
#pragma unroll
  for (int o = 0; o < FO; ++o) acc += Wt[f * FO + o] * a[FO + o];
  wa[f] = acc;
}

// t[row] = dot(h[row, :256], wa)   one wave per row
__global__ __launch_bounds__(256) void k_t(const float* __restrict__ h,
                                           const float* __restrict__ wa,
                                           float* __restrict__ tvec) {
  int lane = threadIdx.x & 63, wave = threadIdx.x >> 6;
  int row = blockIdx.x * 4 + wave;  // 0..B*NT-1
  const float4* hp = (const float4*)(h + (size_t)row * FT);
  const float4* wp = (const float4*)wa;
  float4 hv = hp[lane], wv = wp[lane];
  float acc = hv.x * wv.x + hv.y * wv.y + hv.z * wv.z + hv.w * wv.w;
#pragma unroll
  for (int off = 32; off; off >>= 1) acc += __shfl_down(acc, off);
  if (lane == 0) tvec[row] = acc;
}

// per-batch max of t (softmax shift; any per-row-valid upper bound works)
__global__ __launch_bounds__(256) void k_tmax(const float* __restrict__ tvec,
                                              float* __restrict__ tmax) {
  __shared__ float red[256];
  int b = blockIdx.x, tid = threadIdx.x;
  float m = -3.0e38f;
  for (int j = tid; j < NS; j += 256) m = fmaxf(m, tvec[b * NS + j]);
  red[tid] = m;
  __syncthreads();
  for (int s = 128; s; s >>= 1) {
    if (tid < s) red[tid] = fmaxf(red[tid], red[tid + s]);
    __syncthreads();
  }
  if (tid == 0) tmax[b] = red[0];
}

// Ws_ctx = ctx @ Ws; writes TRANSPOSED bf16 vT[b][f][row] (MFMA B-operand feed)
// and s[row] = Ws_ctx[row,:] @ a[:64].  One wave per 4 rows, 64 lanes = f.
__global__ __launch_bounds__(256) void k_wsctx(const float* __restrict__ ctx,
                                               const float* __restrict__ Ws,
                                               const float* __restrict__ a,
                                               short* __restrict__ vT,
                                               float* __restrict__ svec) {
  const int f = threadIdx.x & 63, wave = threadIdx.x >> 6;
  const int row0 = blockIdx.x * 16 + wave * 4;  // global row in [0, B*NS)
  const float4* c0 = (const float4*)(ctx + (size_t)(row0 + 0) * FS);
  const float4* c1 = (const float4*)(ctx + (size_t)(row0 + 1) * FS);
  const float4* c2 = (const float4*)(ctx + (size_t)(row0 + 2) * FS);
  const float4* c3 = (const float4*)(ctx + (size_t)(row0 + 3) * FS);
  float r0 = 0.f, r1 = 0.f, r2 = 0.f, r3 = 0.f;
#pragma unroll 2
  for (int k4 = 0; k4 < FS / 4; ++k4) {
    const float w0 = Ws[(k4 * 4 + 0) * FO + f];
    const float w1 = Ws[(k4 * 4 + 1) * FO + f];
    const float w2 = Ws[(k4 * 4 + 2) * FO + f];
    const float w3 = Ws[(k4 * 4 + 3) * FO + f];
    float4 x;
    x = c0[k4]; r0 += x.x * w0 + x.y * w1 + x.z * w2 + x.w * w3;
    x = c1[k4]; r1 += x.x * w0 + x.y * w1 + x.z * w2 + x.w * w3;
    x = c2[k4]; r2 += x.x * w0 + x.y * w1 + x.z * w2 + x.w * w3;
    x = c3[k4]; r3 += x.x * w0 + x.y * w1 + x.z * w2 + x.w * w3;
  }
  const int b = row0 >> 12;             // NS = 4096 rows per batch
  const int rloc = row0 & (NS - 1);
  short* vp = vT + ((size_t)b * FO + f) * NS + rloc;
  vp[0] = f2bf(r0); vp[1] = f2bf(r1); vp[2] = f2bf(r2); vp[3] = f2bf(r3);

  const float af = a[f];
  float s0 = r0 * af, s1 = r1 * af, s2 = r2 * af, s3 = r3 * af;
#pragma unroll
  for (int off = 32; off; off >>= 1) {
    s0 += __shfl_down(s0, off);
    s1 += __shfl_down(s1, off);
    s2 += __shfl_down(s2, off);
    s3 += __shfl_down(s3, off);
  }
  if (f == 0) {
    svec[row0 + 0] = s0;
    svec[row0 + 1] = s1;
    svec[row0 + 2] = s2;
    svec[row0 + 3] = s3;
  }
}

// MFMA partial attention: each wave owns 16 rows, computes w on the fly
// (A-frag = 8 consecutive j per lane, generated in-register; no LDS),
// B-frag = 16B contiguous load from vT.  Partials per j-split, no atomics.
__global__ __launch_bounds__(256) void k_part(const int* __restrict__ adj,
                                              const short* __restrict__ vT,
                                              const float* __restrict__ svec,
                                              const float* __restrict__ tvec,
                                              const float* __restrict__ tmax,
                                              float* __restrict__ outpart,
                                              float* __restrict__ lpart) {
  const int lane = threadIdx.x & 63;
  const int wv = threadIdx.x >> 6;   // 0..3
  const int m = lane & 15;           // A row within 16 / B,D col (f within 16)
  const int q = lane >> 4;           // quad: k-offset q*8

  const int tile = blockIdx.x >> 2;      // 256 row-tiles of 64
  const int js = blockIdx.x & (JSPLIT - 1);
  const int b = tile >> 6;               // 64 tiles per batch
  const int i0 = (tile & 63) * 64;
  const int jbase = js * (NS / JSPLIT);

  const int r = i0 + wv * 16 + m;        // this lane's target row (within batch)
  const float sr = svec[b * NS + r];
  const float cr = leaky_max(sr + tmax[b], ALPHA);

  const int* arow = adj + ((size_t)(b * NT) + r) * NS + jbase;
  const float* tp = tvec + b * NS + jbase;
  const short* vp0 = vT + ((size_t)b * FO + m) * NS + jbase;  // + ft*16*NS

  floatx4 acc0 = {0.f, 0.f, 0.f, 0.f};
  floatx4 acc1 = {0.f, 0.f, 0.f, 0.f};
  floatx4 acc2 = {0.f, 0.f, 0.f, 0.f};
  floatx4 acc3 = {0.f, 0.f, 0.f, 0.f};
  float lsum = 0.f;

#pragma unroll 2
  for (int jc = 0; jc < (NS / JSPLIT) / 32; ++jc) {
    const int j0 = jc * 32 + q * 8;
    const int4 a0 = *(const int4*)(arow + j0);
    const int4 a1 = *(const int4*)(arow + j0 + 4);
    const float4 t0 = *(const float4*)(tp + j0);
    const float4 t1 = *(const float4*)(tp + j0 + 4);

    float w[8];
    w[0] = (a0.x > 0) ? __expf(leaky_max(sr + t0.x, ALPHA) - cr) : 0.f;
    w[1] = (a0.y > 0) ? __expf(leaky_max(sr + t0.y, ALPHA) - cr) : 0.f;
    w[2] = (a0.z > 0) ? __expf(leaky_max(sr + t0.z, ALPHA) - cr) : 0.f;
    w[3] = (a0.w > 0) ? __expf(leaky_max(sr + t0.w, ALPHA) - cr) : 0.f;
    w[4] = (a1.x > 0) ? __expf(leaky_max(sr + t1.x, ALPHA) - cr) : 0.f;
    w[5] = (a1.y > 0) ? __expf(leaky_max(sr + t1.y, ALPHA) - cr) : 0.f;
    w[6] = (a1.z > 0) ? __expf(leaky_max(sr + t1.z, ALPHA) - cr) : 0.f;
    w[7] = (a1.w > 0) ? __expf(leaky_max(sr + t1.w, ALPHA) - cr) : 0.f;

    lsum += ((w[0] + w[1]) + (w[2] + w[3])) + ((w[4] + w[5]) + (w[6] + w[7]));

    short8 af;
#pragma unroll
    for (int i = 0; i < 8; ++i) af[i] = f2bf(w[i]);

    const short8 bf0 = *(const short8*)(vp0 + 0 * 16 * NS + j0);
    const short8 bf1 = *(const short8*)(vp0 + 1 * 16 * NS + j0);
    const short8 bf2 = *(const short8*)(vp0 + 2 * 16 * NS + j0);
    const short8 bf3 = *(const short8*)(vp0 + 3 * 16 * NS + j0);
    acc0 = __builtin_amdgcn_mfma_f32_16x16x32_bf16(af, bf0, acc0, 0, 0, 0);
    acc1 = __builtin_amdgcn_mfma_f32_16x16x32_bf16(af, bf1, acc1, 0, 0, 0);
    acc2 = __builtin_amdgcn_mfma_f32_16x16x32_bf16(af, bf2, acc2, 0, 0, 0);
    acc3 = __builtin_amdgcn_mfma_f32_16x16x32_bf16(af, bf3, acc3, 0, 0, 0);
  }

  // denominator partial: reduce lsum over the 4 quads holding the same row m
  float v = lsum;
  v += __shfl_down(v, 32);
  v += __shfl_down(v, 16);
  if (lane < 16) lpart[(size_t)js * BB * NT + (size_t)b * NT + i0 + wv * 16 + m] = v;

  // numerator partial: D layout col=lane&15, row=(lane>>4)*4+reg
  float* op = outpart + (size_t)js * BB * NT * FO +
              ((size_t)(b * NT) + i0 + wv * 16 + q * 4) * FO + m;
#pragma unroll
  for (int reg = 0; reg < 4; ++reg) {
    op[(size_t)reg * FO + 0 * 16] = acc0[reg];
    op[(size_t)reg * FO + 1 * 16] = acc1[reg];
    op[(size_t)reg * FO + 2 * 16] = acc2[reg];
    op[(size_t)reg * FO + 3 * 16] = acc3[reg];
  }
}

// out[i,f] = leaky( (sum_js outpart) / (sum_js lpart), 0.01 ), float4-vectorized
__global__ __launch_bounds__(256) void k_fin(const float* __restrict__ outpart,
                                             const float* __restrict__ lpart,
                                             float* __restrict__ out) {
  const size_t NP = (size_t)BB * NT * FO;   // floats per partial
  const int idx = blockIdx.x * 256 + threadIdx.x;   // float4 index
  const int row = idx >> 4;                          // 16 float4 per row
  float l = lpart[row] + lpart[BB * NT + row] + lpart[2 * BB * NT + row] +
            lpart[3 * BB * NT + row];
  const float inv = 1.f / l;
  float4 v0 = ((const float4*)(outpart + 0 * NP))[idx];
  float4 v1 = ((const float4*)(outpart + 1 * NP))[idx];
  float4 v2 = ((const float4*)(outpart + 2 * NP))[idx];
  float4 v3 = ((const float4*)(outpart + 3 * NP))[idx];
  float4 o;
  o.x = leaky_max((v0.x + v1.x + v2.x + v3.x) * inv, OUT_SLOPE);
  o.y = leaky_max((v0.y + v1.y + v2.y + v3.y) * inv, OUT_SLOPE);
  o.z = leaky_max((v0.z + v1.z + v2.z + v3.z) * inv, OUT_SLOPE);
  o.w = leaky_max((v0.w + v1.w + v2.w + v3.w) * inv, OUT_SLOPE);
  ((float4*)out)[idx] = o;
}

extern "C" void kernel_launch(void* const* d_in, const int* in_sizes, int n_in,
                              void* d_out, int out_size, void* d_ws, size_t ws_size,
                              hipStream_t stream) {
  const float* h   = (const float*)d_in[0];  // [B, Nt, Ft]
  const float* ctx = (const float*)d_in[1];  // [B, Ns, Fs]
  const int*   adj = (const int*)d_in[2];    // [B, Nt, Ns]
  const float* Ws  = (const float*)d_in[3];  // [Fs, Fo]
  const float* Wt  = (const float*)d_in[4];  // [Ft, Fo]
  const float* a   = (const float*)d_in[5];  // [2*Fo, 1]
  float* out = (float*)d_out;                // [B, Nt, Fo] fp32
  float* ws = (float*)d_ws;

  // workspace layout (floats), total ~19.3 MB; every element written before read
  float* outpart = ws;                               // JSPLIT * B*NT*FO = 4,194,304
  float* lpart   = outpart + (size_t)JSPLIT * BB * NT * FO;  // JSPLIT * B*NT = 65,536
  float* tvec    = lpart + (size_t)JSPLIT * BB * NT;  // 16384
  float* svec    = tvec + BB * NS;                    // 16384
  float* wa      = svec + BB * NS;                    // 256
  float* tmax    = wa + 256;                          // 4
  short* vT      = (short*)(tmax + 4);                // B*FO*NS bf16 = 2 MB

  k_wa<<<1, 256, 0, stream>>>(Wt, a, wa);
  k_t<<<(BB * NT) / 4, 256, 0, stream>>>(h, wa, tvec);
  k_tmax<<<BB, 256, 0, stream>>>(tvec, tmax);
  k_wsctx<<<(BB * NS) / 16, 256, 0, stream>>>(ctx, Ws, a, vT, svec);
  k_part<<<(BB * NT / 64) * JSPLIT, 256, 0, stream>>>(adj, vT, svec, tvec, tmax,
                                                      outpart, lpart);
  k_fin<<<(BB * NT * FO / 4) / 256, 256, 0, stream>>>(outpart, lpart, out);
}